// Round 7
// baseline (139.286 us; speedup 1.0000x reference)
//
#include <hip/hip_runtime.h>

// YOLOv1 loss, MI355X. preds/targets: (16384,7,7,30) f32 -> 3 f32 losses.
// R7: R4's lazy-load body (best: 38.9us) + tail fused via RELAXED device-scope
// float atomicAdd of pre-scaled block partials into d_out (no fences, no
// counter, no second kernel). R2/R3's poison was the acq-rel fence semantics,
// not atomic throughput: 3x3136 relaxed near-atomics pipeline in TCC.

constexpr int   CH      = 30;              // dwords per cell
constexpr int   NCELL   = 16384 * 7 * 7;   // 802816
constexpr int   BLK     = 256;
constexpr int   NBLK    = NCELL / BLK;     // 3136
constexpr float INV_GS  = 1.0f / 7.0f;
constexpr float INV_BS  = 1.0f / 16384.0f;
constexpr float L_COORD = 5.0f;
constexpr float L_NOOBJ = 0.5f;

__global__ __launch_bounds__(BLK) void yolo_loss_fused(
    const float* __restrict__ preds,
    const float* __restrict__ targets,
    float* __restrict__ out)   // [3], zeroed by memset on stream
{
    const int n = blockIdx.x * BLK + threadIdx.x;
    const float* __restrict__ P = preds   + (size_t)n * CH;
    const float* __restrict__ T = targets + (size_t)n * CH;

    // --- minimal loads (all cells) ---
    const float t4 = T[4];
    const float p4 = P[4];
    const float p9 = P[9];
    const bool  obj = t4 > 0.f;

    float s_box = 0.f, s_obj = 0.f, s_cls = 0.f;

    if (obj) {
        // --- obj path (~6% of lanes), loads under exec mask ---
        const float p0 = P[0], p1 = P[1], p2 = P[2], p3 = P[3];
        const float p5 = P[5], p6 = P[6], p7 = P[7], p8 = P[8];
        const float t0 = T[0], t1 = T[1], t2 = T[2], t3 = T[3];

        const float tx = t0 * INV_GS, ty = t1 * INV_GS;
        const float tax0 = tx - 0.5f * t2, tay0 = ty - 0.5f * t3;
        const float tax1 = tx + 0.5f * t2, tay1 = ty + 0.5f * t3;
        const float area_t = t2 * t3;

        float iou0, iou1;
        {
            float px = p0 * INV_GS, py = p1 * INV_GS;
            float ax0 = px - 0.5f * p2, ay0 = py - 0.5f * p3;
            float ax1 = px + 0.5f * p2, ay1 = py + 0.5f * p3;
            float iw = fmaxf(fminf(ax1, tax1) - fmaxf(ax0, tax0), 0.f);
            float ih = fmaxf(fminf(ay1, tay1) - fmaxf(ay0, tay0), 0.f);
            float inter = iw * ih;
            iou0 = inter / (p2 * p3 + area_t - inter);
        }
        {
            float px = p5 * INV_GS, py = p6 * INV_GS;
            float ax0 = px - 0.5f * p7, ay0 = py - 0.5f * p8;
            float ax1 = px + 0.5f * p7, ay1 = py + 0.5f * p8;
            float iw = fmaxf(fminf(ax1, tax1) - fmaxf(ax0, tax0), 0.f);
            float ih = fmaxf(fminf(ay1, tay1) - fmaxf(ay0, tay0), 0.f);
            float inter = iw * ih;
            iou1 = inter / (p7 * p8 + area_t - inter);
        }

        const bool  sel     = iou1 > iou0;        // first-max tie-break
        const float max_iou = fmaxf(iou0, iou1);
        const float rx = sel ? p5 : p0;
        const float ry = sel ? p6 : p1;
        const float rw = sel ? p7 : p2;
        const float rh = sel ? p8 : p3;
        const float rc = sel ? p9 : p4;

        float dx = rx - t0, dy = ry - t1;
        float sw = sqrtf(rw) - sqrtf(t2);
        float sh = sqrtf(rh) - sqrtf(t3);
        s_box = dx * dx + dy * dy + sw * sw + sh * sh;

        float dc = rc - max_iou;
        s_obj = dc * dc;

        float acc = 0.f;
        #pragma unroll
        for (int k = 10; k < 30; ++k) {
            float d = P[k] - T[k];
            acc += d * d;
        }
        s_cls = acc;
    } else {
        // noobj: t[4]==t[9]==0 by construction
        s_obj = L_NOOBJ * (p4 * p4 + p9 * p9);
    }

    // --- wave + block reduce ---
    #pragma unroll
    for (int off = 32; off > 0; off >>= 1) {
        s_box += __shfl_down(s_box, off);
        s_obj += __shfl_down(s_obj, off);
        s_cls += __shfl_down(s_cls, off);
    }

    __shared__ float red[3][BLK / 64];
    const int wid  = threadIdx.x >> 6;
    const int lane = threadIdx.x & 63;
    if (lane == 0) { red[0][wid] = s_box; red[1][wid] = s_obj; red[2][wid] = s_cls; }
    __syncthreads();
    if (threadIdx.x == 0) {
        float b = red[0][0] + red[0][1] + red[0][2] + red[0][3];
        float o = red[1][0] + red[1][1] + red[1][2] + red[1][3];
        float c = red[2][0] + red[2][1] + red[2][2] + red[2][3];
        // pre-scaled relaxed atomics (device scope, NO fence)
        __hip_atomic_fetch_add(&out[0], L_COORD * INV_BS * b,
                               __ATOMIC_RELAXED, __HIP_MEMORY_SCOPE_AGENT);
        __hip_atomic_fetch_add(&out[1], INV_BS * o,
                               __ATOMIC_RELAXED, __HIP_MEMORY_SCOPE_AGENT);
        __hip_atomic_fetch_add(&out[2], INV_BS * c,
                               __ATOMIC_RELAXED, __HIP_MEMORY_SCOPE_AGENT);
    }
}

extern "C" void kernel_launch(void* const* d_in, const int* in_sizes, int n_in,
                              void* d_out, int out_size, void* d_ws, size_t ws_size,
                              hipStream_t stream) {
    const float* preds   = (const float*)d_in[0];
    const float* targets = (const float*)d_in[1];
    float* out = (float*)d_out;

    hipMemsetAsync(out, 0, 3 * sizeof(float), stream);
    yolo_loss_fused<<<NBLK, BLK, 0, stream>>>(preds, targets, out);
}

// Round 8
// 46.706 us; speedup vs baseline: 2.9822x; 2.9822x over previous
//
#include <hip/hip_runtime.h>

// YOLOv1 loss, MI355X. preds/targets: (16384,7,7,30) f32 -> 3 f32 losses.
// R8: R4's lazy-load two-kernel structure (best: 38.9us), with all global
// reads as __builtin_nontemporal_load (nt=1). Discriminates L1-outstanding-
// miss-bound (expect ~25us) vs fabric-BW-bound (~38us, roofline).

constexpr int   CH      = 30;              // dwords per cell
constexpr int   NCELL   = 16384 * 7 * 7;   // 802816
constexpr int   BLK     = 256;
constexpr int   NBLK    = NCELL / BLK;     // 3136
constexpr float INV_GS  = 1.0f / 7.0f;
constexpr float INV_BS  = 1.0f / 16384.0f;
constexpr float L_COORD = 5.0f;
constexpr float L_NOOBJ = 0.5f;

__device__ __forceinline__ float ldnt(const float* p) {
    return __builtin_nontemporal_load(p);
}

__global__ __launch_bounds__(BLK) void yolo_loss_partial(
    const float* __restrict__ preds,
    const float* __restrict__ targets,
    float* __restrict__ part)   // [3][NBLK] raw sums
{
    const int n = blockIdx.x * BLK + threadIdx.x;
    const float* __restrict__ P = preds   + (size_t)n * CH;
    const float* __restrict__ T = targets + (size_t)n * CH;

    // --- minimal loads (all cells) ---
    const float t4 = ldnt(T + 4);
    const float p4 = ldnt(P + 4);
    const float p9 = ldnt(P + 9);
    const bool  obj = t4 > 0.f;

    float s_box = 0.f, s_obj = 0.f, s_cls = 0.f;

    if (obj) {
        // --- obj path (~6% of lanes), loads under exec mask ---
        const float p0 = ldnt(P + 0), p1 = ldnt(P + 1), p2 = ldnt(P + 2), p3 = ldnt(P + 3);
        const float p5 = ldnt(P + 5), p6 = ldnt(P + 6), p7 = ldnt(P + 7), p8 = ldnt(P + 8);
        const float t0 = ldnt(T + 0), t1 = ldnt(T + 1), t2 = ldnt(T + 2), t3 = ldnt(T + 3);

        const float tx = t0 * INV_GS, ty = t1 * INV_GS;
        const float tax0 = tx - 0.5f * t2, tay0 = ty - 0.5f * t3;
        const float tax1 = tx + 0.5f * t2, tay1 = ty + 0.5f * t3;
        const float area_t = t2 * t3;

        float iou0, iou1;
        {
            float px = p0 * INV_GS, py = p1 * INV_GS;
            float ax0 = px - 0.5f * p2, ay0 = py - 0.5f * p3;
            float ax1 = px + 0.5f * p2, ay1 = py + 0.5f * p3;
            float iw = fmaxf(fminf(ax1, tax1) - fmaxf(ax0, tax0), 0.f);
            float ih = fmaxf(fminf(ay1, tay1) - fmaxf(ay0, tay0), 0.f);
            float inter = iw * ih;
            iou0 = inter / (p2 * p3 + area_t - inter);
        }
        {
            float px = p5 * INV_GS, py = p6 * INV_GS;
            float ax0 = px - 0.5f * p7, ay0 = py - 0.5f * p8;
            float ax1 = px + 0.5f * p7, ay1 = py + 0.5f * p8;
            float iw = fmaxf(fminf(ax1, tax1) - fmaxf(ax0, tax0), 0.f);
            float ih = fmaxf(fminf(ay1, tay1) - fmaxf(ay0, tay0), 0.f);
            float inter = iw * ih;
            iou1 = inter / (p7 * p8 + area_t - inter);
        }

        const bool  sel     = iou1 > iou0;        // first-max tie-break
        const float max_iou = fmaxf(iou0, iou1);
        const float rx = sel ? p5 : p0;
        const float ry = sel ? p6 : p1;
        const float rw = sel ? p7 : p2;
        const float rh = sel ? p8 : p3;
        const float rc = sel ? p9 : p4;

        float dx = rx - t0, dy = ry - t1;
        float sw = sqrtf(rw) - sqrtf(t2);
        float sh = sqrtf(rh) - sqrtf(t3);
        s_box = dx * dx + dy * dy + sw * sw + sh * sh;

        float dc = rc - max_iou;
        s_obj = dc * dc;

        float acc = 0.f;
        #pragma unroll
        for (int k = 10; k < 30; ++k) {
            float d = ldnt(P + k) - ldnt(T + k);
            acc += d * d;
        }
        s_cls = acc;
    } else {
        // noobj: t[4]==t[9]==0 by construction
        s_obj = L_NOOBJ * (p4 * p4 + p9 * p9);
    }

    // --- wave + block reduce ---
    #pragma unroll
    for (int off = 32; off > 0; off >>= 1) {
        s_box += __shfl_down(s_box, off);
        s_obj += __shfl_down(s_obj, off);
        s_cls += __shfl_down(s_cls, off);
    }

    __shared__ float red[3][BLK / 64];
    const int wid  = threadIdx.x >> 6;
    const int lane = threadIdx.x & 63;
    if (lane == 0) { red[0][wid] = s_box; red[1][wid] = s_obj; red[2][wid] = s_cls; }
    __syncthreads();
    if (threadIdx.x == 0) {
        float b = red[0][0] + red[0][1] + red[0][2] + red[0][3];
        float o = red[1][0] + red[1][1] + red[1][2] + red[1][3];
        float c = red[2][0] + red[2][1] + red[2][2] + red[2][3];
        part[0 * NBLK + blockIdx.x] = b;
        part[1 * NBLK + blockIdx.x] = o;
        part[2 * NBLK + blockIdx.x] = c;
    }
}

__global__ __launch_bounds__(256) void yolo_loss_reduce(
    const float* __restrict__ part, float* __restrict__ out)
{
    float s0 = 0.f, s1 = 0.f, s2 = 0.f;
    for (int i = threadIdx.x; i < NBLK; i += 256) {
        s0 += part[0 * NBLK + i];
        s1 += part[1 * NBLK + i];
        s2 += part[2 * NBLK + i];
    }
    #pragma unroll
    for (int off = 32; off > 0; off >>= 1) {
        s0 += __shfl_down(s0, off);
        s1 += __shfl_down(s1, off);
        s2 += __shfl_down(s2, off);
    }
    __shared__ float red[3][4];
    const int wid  = threadIdx.x >> 6;
    const int lane = threadIdx.x & 63;
    if (lane == 0) { red[0][wid] = s0; red[1][wid] = s1; red[2][wid] = s2; }
    __syncthreads();
    if (threadIdx.x == 0) {
        float b = red[0][0] + red[0][1] + red[0][2] + red[0][3];
        float o = red[1][0] + red[1][1] + red[1][2] + red[1][3];
        float c = red[2][0] + red[2][1] + red[2][2] + red[2][3];
        out[0] = L_COORD * b * INV_BS;
        out[1] = o * INV_BS;
        out[2] = c * INV_BS;
    }
}

extern "C" void kernel_launch(void* const* d_in, const int* in_sizes, int n_in,
                              void* d_out, int out_size, void* d_ws, size_t ws_size,
                              hipStream_t stream) {
    const float* preds   = (const float*)d_in[0];
    const float* targets = (const float*)d_in[1];
    float* out  = (float*)d_out;
    float* part = (float*)d_ws;   // 3*NBLK floats = 37632 B

    yolo_loss_partial<<<NBLK, BLK, 0, stream>>>(preds, targets, part);
    yolo_loss_reduce<<<1, 256, 0, stream>>>(part, out);
}

// Round 9
// 41.750 us; speedup vs baseline: 3.3362x; 1.1187x over previous
//
#include <hip/hip_runtime.h>

// YOLOv1 loss, MI355X. preds/targets: (16384,7,7,30) f32 -> 3 f32 losses.
// R9: R4 lazy body, 2 cells/thread at stride NCELL/2 (both streams keep the
// proven 120-B lane stride; R6's failure was its 240-B stride, not CPT=2).
// 1568 blocks, doubled per-thread MLP, half the tail partials.

constexpr int   CH      = 30;              // dwords per cell
constexpr int   NCELL   = 16384 * 7 * 7;   // 802816
constexpr int   BLK     = 256;
constexpr int   HALF    = NCELL / 2;       // 401408
constexpr int   NBLK    = HALF / BLK;      // 1568
constexpr float INV_GS  = 1.0f / 7.0f;
constexpr float INV_BS  = 1.0f / 16384.0f;
constexpr float L_COORD = 5.0f;
constexpr float L_NOOBJ = 0.5f;

__device__ __forceinline__ void cell_loss(
    const float* __restrict__ P, const float* __restrict__ T,
    float& s_box, float& s_obj, float& s_cls)
{
    const float t4 = T[4];
    const float p4 = P[4];
    const float p9 = P[9];
    const bool  obj = t4 > 0.f;

    if (obj) {
        const float p0 = P[0], p1 = P[1], p2 = P[2], p3 = P[3];
        const float p5 = P[5], p6 = P[6], p7 = P[7], p8 = P[8];
        const float t0 = T[0], t1 = T[1], t2 = T[2], t3 = T[3];

        const float tx = t0 * INV_GS, ty = t1 * INV_GS;
        const float tax0 = tx - 0.5f * t2, tay0 = ty - 0.5f * t3;
        const float tax1 = tx + 0.5f * t2, tay1 = ty + 0.5f * t3;
        const float area_t = t2 * t3;

        float iou0, iou1;
        {
            float px = p0 * INV_GS, py = p1 * INV_GS;
            float ax0 = px - 0.5f * p2, ay0 = py - 0.5f * p3;
            float ax1 = px + 0.5f * p2, ay1 = py + 0.5f * p3;
            float iw = fmaxf(fminf(ax1, tax1) - fmaxf(ax0, tax0), 0.f);
            float ih = fmaxf(fminf(ay1, tay1) - fmaxf(ay0, tay0), 0.f);
            float inter = iw * ih;
            iou0 = inter / (p2 * p3 + area_t - inter);
        }
        {
            float px = p5 * INV_GS, py = p6 * INV_GS;
            float ax0 = px - 0.5f * p7, ay0 = py - 0.5f * p8;
            float ax1 = px + 0.5f * p7, ay1 = py + 0.5f * p8;
            float iw = fmaxf(fminf(ax1, tax1) - fmaxf(ax0, tax0), 0.f);
            float ih = fmaxf(fminf(ay1, tay1) - fmaxf(ay0, tay0), 0.f);
            float inter = iw * ih;
            iou1 = inter / (p7 * p8 + area_t - inter);
        }

        const bool  sel     = iou1 > iou0;        // first-max tie-break
        const float max_iou = fmaxf(iou0, iou1);
        const float rx = sel ? p5 : p0;
        const float ry = sel ? p6 : p1;
        const float rw = sel ? p7 : p2;
        const float rh = sel ? p8 : p3;
        const float rc = sel ? p9 : p4;

        float dx = rx - t0, dy = ry - t1;
        float sw = sqrtf(rw) - sqrtf(t2);
        float sh = sqrtf(rh) - sqrtf(t3);
        s_box += dx * dx + dy * dy + sw * sw + sh * sh;

        float dc = rc - max_iou;
        s_obj += dc * dc;

        float acc = 0.f;
        #pragma unroll
        for (int k = 10; k < 30; ++k) {
            float d = P[k] - T[k];
            acc += d * d;
        }
        s_cls += acc;
    } else {
        // noobj: t[4]==t[9]==0 by construction
        s_obj += L_NOOBJ * (p4 * p4 + p9 * p9);
    }
}

__global__ __launch_bounds__(BLK) void yolo_loss_partial(
    const float* __restrict__ preds,
    const float* __restrict__ targets,
    float* __restrict__ part)   // [3][NBLK] raw sums
{
    const int n = blockIdx.x * BLK + threadIdx.x;   // cell in first half

    float s_box = 0.f, s_obj = 0.f, s_cls = 0.f;
    cell_loss(preds + (size_t)n * CH,           targets + (size_t)n * CH,           s_box, s_obj, s_cls);
    cell_loss(preds + (size_t)(n + HALF) * CH,  targets + (size_t)(n + HALF) * CH,  s_box, s_obj, s_cls);

    // --- wave + block reduce ---
    #pragma unroll
    for (int off = 32; off > 0; off >>= 1) {
        s_box += __shfl_down(s_box, off);
        s_obj += __shfl_down(s_obj, off);
        s_cls += __shfl_down(s_cls, off);
    }

    __shared__ float red[3][BLK / 64];
    const int wid  = threadIdx.x >> 6;
    const int lane = threadIdx.x & 63;
    if (lane == 0) { red[0][wid] = s_box; red[1][wid] = s_obj; red[2][wid] = s_cls; }
    __syncthreads();
    if (threadIdx.x == 0) {
        float b = red[0][0] + red[0][1] + red[0][2] + red[0][3];
        float o = red[1][0] + red[1][1] + red[1][2] + red[1][3];
        float c = red[2][0] + red[2][1] + red[2][2] + red[2][3];
        part[0 * NBLK + blockIdx.x] = b;
        part[1 * NBLK + blockIdx.x] = o;
        part[2 * NBLK + blockIdx.x] = c;
    }
}

__global__ __launch_bounds__(256) void yolo_loss_reduce(
    const float* __restrict__ part, float* __restrict__ out)
{
    float s0 = 0.f, s1 = 0.f, s2 = 0.f;
    for (int i = threadIdx.x; i < NBLK; i += 256) {
        s0 += part[0 * NBLK + i];
        s1 += part[1 * NBLK + i];
        s2 += part[2 * NBLK + i];
    }
    #pragma unroll
    for (int off = 32; off > 0; off >>= 1) {
        s0 += __shfl_down(s0, off);
        s1 += __shfl_down(s1, off);
        s2 += __shfl_down(s2, off);
    }
    __shared__ float red[3][4];
    const int wid  = threadIdx.x >> 6;
    const int lane = threadIdx.x & 63;
    if (lane == 0) { red[0][wid] = s0; red[1][wid] = s1; red[2][wid] = s2; }
    __syncthreads();
    if (threadIdx.x == 0) {
        float b = red[0][0] + red[0][1] + red[0][2] + red[0][3];
        float o = red[1][0] + red[1][1] + red[1][2] + red[1][3];
        float c = red[2][0] + red[2][1] + red[2][2] + red[2][3];
        out[0] = L_COORD * b * INV_BS;
        out[1] = o * INV_BS;
        out[2] = c * INV_BS;
    }
}

extern "C" void kernel_launch(void* const* d_in, const int* in_sizes, int n_in,
                              void* d_out, int out_size, void* d_ws, size_t ws_size,
                              hipStream_t stream) {
    const float* preds   = (const float*)d_in[0];
    const float* targets = (const float*)d_in[1];
    float* out  = (float*)d_out;
    float* part = (float*)d_ws;   // 3*NBLK floats = 18816 B

    yolo_loss_partial<<<NBLK, BLK, 0, stream>>>(preds, targets, part);
    yolo_loss_reduce<<<1, 256, 0, stream>>>(part, out);
}